// Round 4
// baseline (577.702 us; speedup 1.0000x reference)
//
#include <hip/hip_runtime.h>
#include <hip/hip_fp16.h>
#include <math.h>

typedef _Float16 half_t;
typedef half_t half4_t __attribute__((ext_vector_type(4)));
typedef half_t half8_t __attribute__((ext_vector_type(8)));
typedef float f32x4 __attribute__((ext_vector_type(4)));

#define LN_EPS 1e-5f

// ---------------------------------------------------------------------------
// Pack W*g (LN gain folded) into f16 MFMA B-fragment order:
//   packed[((cbg*T + t)*64 + l)*8 + j] = (f16)(W[16*cbg+(l&15)][32t+8*(l>>4)+j] * g[k])
// ---------------------------------------------------------------------------
__global__ void pack_weights(const float* __restrict__ W0, const float* __restrict__ g0,
                             const float* __restrict__ W1, const float* __restrict__ g1,
                             const float* __restrict__ W2, const float* __restrict__ g2,
                             half_t* __restrict__ ws) {
    int sid = blockIdx.x * 256 + threadIdx.x;
    const float* W; const float* g; int K, T, off;
    if (sid < 49152)      { W = W0; g = g0; K = 768; T = 24; off = 0; }
    else if (sid < 65536) { W = W1; g = g1; K = 512; T = 16; off = 49152; sid -= 49152; }
    else if (sid < 69632) { W = W2; g = g2; K = 256; T = 8;  off = 65536; sid -= 65536; }
    else return;
    const int l   = sid & 63;
    const int t   = (sid >> 6) % T;
    const int cbg = (sid >> 6) / T;
    const int n   = (l & 15) + 16 * cbg;
    const int k0  = 32 * t + 8 * (l >> 4);
    const float* src = W + (size_t)n * K + k0;
    const float* gs  = g + k0;
    half8_t v;
    #pragma unroll
    for (int jq = 0; jq < 8; jq++) v[jq] = (half_t)(src[jq] * gs[jq]);
    *(half8_t*)(ws + (size_t)(off + sid) * 8) = v;
}

// ---------------------------------------------------------------------------
// Fold LN bias into per-output scalars: s[n]=sum_k W[n,k]*g[k],
// c'[n]=sum_k W[n,k]*b[k]+c[n]. f layout:
// s0[512] c0[512] s1[256] c1[256] s2[128] c2[128] w3g[128] s3 c3'
// ---------------------------------------------------------------------------
__global__ void fold_bias(const float* __restrict__ W0, const float* __restrict__ g0,
                          const float* __restrict__ b0, const float* __restrict__ c0,
                          const float* __restrict__ W1, const float* __restrict__ g1,
                          const float* __restrict__ b1, const float* __restrict__ c1,
                          const float* __restrict__ W2, const float* __restrict__ g2,
                          const float* __restrict__ b2, const float* __restrict__ c2,
                          const float* __restrict__ W3, const float* __restrict__ g3,
                          const float* __restrict__ b3, const float* __restrict__ c3,
                          float* __restrict__ f) {
    const int gw   = (blockIdx.x * 256 + threadIdx.x) >> 6;
    const int lane = threadIdx.x & 63;
    if (gw == 896) {
        float s = 0.f, cb_ = 0.f;
        for (int k = lane; k < 128; k += 64) {
            const float wg = W3[k] * g3[k];
            f[1792 + k] = wg;
            s += wg; cb_ += W3[k] * b3[k];
        }
        #pragma unroll
        for (int m = 1; m < 64; m <<= 1) { s += __shfl_xor(s, m); cb_ += __shfl_xor(cb_, m); }
        if (lane == 0) { f[1920] = s; f[1921] = cb_ + c3[0]; }
        return;
    }
    const float *W, *g, *b, *cc; int K, n; float *sf, *cf;
    if (gw < 512)      { W = W0; g = g0; b = b0; cc = c0; K = 768; n = gw;       sf = f;        cf = f + 512; }
    else if (gw < 768) { W = W1; g = g1; b = b1; cc = c1; K = 512; n = gw - 512; sf = f + 1024; cf = f + 1280; }
    else if (gw < 896) { W = W2; g = g2; b = b2; cc = c2; K = 256; n = gw - 768; sf = f + 1536; cf = f + 1664; }
    else return;
    const float* Wr = W + (size_t)n * K;
    float s = 0.f, cb_ = 0.f;
    for (int k = lane; k < K; k += 64) { const float wg = Wr[k] * g[k]; s += wg; cb_ += Wr[k] * b[k]; }
    #pragma unroll
    for (int m = 1; m < 64; m <<= 1) { s += __shfl_xor(s, m); cb_ += __shfl_xor(cb_, m); }
    if (lane == 0) { sf[n] = s; cf[n] = cb_ + cc[n]; }
}

// ---------------------------------------------------------------------------
// Fused MLP: 64 rows/block, 512 threads (8 waves), 2 blocks/CU (4 waves/SIMD)
// so co-resident blocks at different phases cross-hide HBM/L2/LDS latency.
// LN folded into weights; B-fragments register-double-buffered from L2;
// x staging split load-early/write-late (T14).
// ---------------------------------------------------------------------------
__global__ __launch_bounds__(512, 4)
void fused_mlp(const float* __restrict__ x_in,
               const half_t* __restrict__ W0p, const half_t* __restrict__ W1p,
               const half_t* __restrict__ W2p, const float* __restrict__ f,
               float* __restrict__ out)
{
    __shared__ half_t frag[32768];                 // 64 KiB: x1; staging bufs alias [0,16K)x2
    __shared__ float psum[8][64], psq[8][64], pdot[8][64];
    __shared__ float row_m[64], row_rs[64];

    const int tid  = threadIdx.x;
    const int lane = tid & 63;
    const int wv   = tid >> 6;       // wave 0..7
    const int grp  = lane >> 4;
    const int cl   = lane & 15;
    const int row  = tid >> 3;       // staging row 0..63
    const int jj   = tid & 7;        // 8 threads per row
    const int rbw  = row >> 4;       // 0..3
    const long r0  = (long)blockIdx.x * 64;
    const float* xrow = x_in + (r0 + row) * 768;

    const float* s0f = f;        const float* c0f = f + 512;
    const float* s1f = f + 1024; const float* c1f = f + 1280;
    const float* s2f = f + 1536; const float* c2f = f + 1664;
    const float* w3f = f + 1792;

    float s = 0.f, ss = 0.f;
    f32x4 vb[4];

    // issue global loads for K-chunk c (128 cols) into regs
    auto stage_load = [&](int c) {
        const float* xp = xrow + 128 * c + 4 * jj;
        #pragma unroll
        for (int i = 0; i < 4; i++)
            vb[i] = __builtin_nontemporal_load((const f32x4*)(xp + 32 * i));
    };
    // stats + f16 convert + fragment ds_write for chunk c
    auto stage_write = [&](int c) {
        half_t* fb = frag + 8192 * (c & 1);
        const int hg = jj >> 1, jo = 4 * (jj & 1);
        #pragma unroll
        for (int i = 0; i < 4; i++) {
            const f32x4 v = vb[i];
            s  += v[0] + v[1] + v[2] + v[3];
            ss += v[0]*v[0] + v[1]*v[1] + v[2]*v[2] + v[3]*v[3];
            half4_t hv;
            hv[0] = (half_t)v[0]; hv[1] = (half_t)v[1];
            hv[2] = (half_t)v[2]; hv[3] = (half_t)v[3];
            *(half4_t*)(&fb[((i * 4 + rbw) * 64 + ((row & 15) + 16 * hg)) * 8 + jo]) = hv;
        }
    };

    f32x4 acc0[4][4];
    #pragma unroll
    for (int rb = 0; rb < 4; rb++)
        #pragma unroll
        for (int cb = 0; cb < 4; cb++) acc0[rb][cb] = 0.f;

    // GEMM0 chunk: 4 t-steps, B register-double-buffered from L2
    auto gemm0 = [&](int c) {
        const half_t* fb = frag + 8192 * (c & 1);
        const half_t* wp = W0p + (size_t)(4 * wv * 24 + 4 * c) * 512 + lane * 8;
        half8_t bA[4], bB[4];
        #pragma unroll
        for (int cb = 0; cb < 4; cb++) bA[cb] = *(const half8_t*)(wp + cb * 12288);
        #pragma unroll
        for (int tt = 0; tt < 4; tt++) {
            half8_t* cur = (tt & 1) ? bB : bA;
            half8_t* nxt = (tt & 1) ? bA : bB;
            if (tt < 3) {
                #pragma unroll
                for (int cb = 0; cb < 4; cb++)
                    nxt[cb] = *(const half8_t*)(wp + (tt + 1) * 512 + cb * 12288);
            }
            half8_t af[4];
            #pragma unroll
            for (int rb = 0; rb < 4; rb++)
                af[rb] = *(const half8_t*)(&fb[((tt * 4 + rb) * 64 + lane) * 8]);
            #pragma unroll
            for (int cb = 0; cb < 4; cb++)
                #pragma unroll
                for (int rb = 0; rb < 4; rb++)
                    acc0[rb][cb] = __builtin_amdgcn_mfma_f32_16x16x32_f16(af[rb], cur[cb], acc0[rb][cb], 0, 0, 0);
        }
    };

    // ---- pipeline: 6 chunks of K=128 ----
    stage_load(0); stage_write(0);
    __syncthreads();
    #pragma unroll 1
    for (int c = 0; c < 6; c++) {
        if (c < 5) stage_load(c + 1);     // HBM loads in flight during MFMA
        gemm0(c);
        if (c < 5) stage_write(c + 1);    // convert+LDS write after compute
        if (c == 4) {                     // all 6 chunks' stats accumulated
            s  += __shfl_xor(s, 1);  s  += __shfl_xor(s, 2);  s  += __shfl_xor(s, 4);
            ss += __shfl_xor(ss, 1); ss += __shfl_xor(ss, 2); ss += __shfl_xor(ss, 4);
            if (jj == 0) {
                const float mm = s * (1.f / 768.f);
                row_m[row]  = mm;
                row_rs[row] = 1.f / sqrtf(ss * (1.f / 768.f) - mm * mm + LN_EPS);
            }
        }
        __syncthreads();
    }

    // ---- epilogue0: LN0 fold + ELU + LN1 partials + x1 fragment writes ----
    {
        float sv[4], cv[4];
        #pragma unroll
        for (int cb = 0; cb < 4; cb++) {
            const int c = cl + 16 * (4 * wv + cb);
            sv[cb] = s0f[c]; cv[cb] = c0f[c];
        }
        #pragma unroll
        for (int rb = 0; rb < 4; rb++)
            #pragma unroll
            for (int v = 0; v < 4; v++) {
                const int r = 16 * rb + 4 * grp + v;
                const float rm = row_m[r], rr = row_rs[r];
                float a_ = 0.f, q_ = 0.f;
                #pragma unroll
                for (int cb = 0; cb < 4; cb++) {
                    float y = rr * (acc0[rb][cb][v] - rm * sv[cb]) + cv[cb];
                    y = y > 0.f ? y : (__expf(y) - 1.f);
                    acc0[rb][cb][v] = y;
                    a_ += y; q_ += y * y;
                }
                a_ += __shfl_xor(a_, 1); a_ += __shfl_xor(a_, 2); a_ += __shfl_xor(a_, 4); a_ += __shfl_xor(a_, 8);
                q_ += __shfl_xor(q_, 1); q_ += __shfl_xor(q_, 2); q_ += __shfl_xor(q_, 4); q_ += __shfl_xor(q_, 8);
                if (cl == 0) { psum[wv][r] = a_; psq[wv][r] = q_; }
            }
        #pragma unroll
        for (int cb = 0; cb < 4; cb++) {
            const int c = cl + 16 * (4 * wv + cb);
            const int t = c >> 5, j = c & 7, sc = 16 * ((c >> 3) & 3);
            #pragma unroll
            for (int rb = 0; rb < 4; rb++)
                #pragma unroll
                for (int v = 0; v < 4; v++)
                    frag[((t * 4 + rb) * 64 + (4 * grp + v + sc)) * 8 + j] = (half_t)acc0[rb][cb][v];
        }
    }
    __syncthreads();
    if (tid < 64) {
        float a_ = 0.f, q_ = 0.f;
        #pragma unroll
        for (int w = 0; w < 8; w++) { a_ += psum[w][tid]; q_ += psq[w][tid]; }
        const float mm = a_ * (1.f / 512.f);
        row_m[tid]  = mm;
        row_rs[tid] = 1.f / sqrtf(q_ * (1.f / 512.f) - mm * mm + LN_EPS);
    }
    __syncthreads();

    // ---- GEMM1: K=512 (16 t-steps), wave owns 32 cols, B prefetched ----
    f32x4 acc1[4][2];
    #pragma unroll
    for (int rb = 0; rb < 4; rb++) { acc1[rb][0] = 0.f; acc1[rb][1] = 0.f; }
    {
        const half_t* wp = W1p + (size_t)(2 * wv * 16) * 512 + lane * 8;
        half8_t bA[2], bB[2];
        bA[0] = *(const half8_t*)(wp);
        bA[1] = *(const half8_t*)(wp + 8192);
        #pragma unroll
        for (int t = 0; t < 16; t++) {
            half8_t* cur = (t & 1) ? bB : bA;
            half8_t* nxt = (t & 1) ? bA : bB;
            if (t < 15) {
                nxt[0] = *(const half8_t*)(wp + (t + 1) * 512);
                nxt[1] = *(const half8_t*)(wp + (t + 1) * 512 + 8192);
            }
            half8_t af[4];
            #pragma unroll
            for (int rb = 0; rb < 4; rb++)
                af[rb] = *(const half8_t*)(&frag[((t * 4 + rb) * 64 + lane) * 8]);
            #pragma unroll
            for (int cb = 0; cb < 2; cb++)
                #pragma unroll
                for (int rb = 0; rb < 4; rb++)
                    acc1[rb][cb] = __builtin_amdgcn_mfma_f32_16x16x32_f16(af[rb], cur[cb], acc1[rb][cb], 0, 0, 0);
        }
    }

    // ---- epilogue1: LN1 fold + ELU + LN2 partials (regs only) ----
    {
        float sv[2], cv[2];
        #pragma unroll
        for (int cb = 0; cb < 2; cb++) {
            const int c = cl + 16 * (2 * wv + cb);
            sv[cb] = s1f[c]; cv[cb] = c1f[c];
        }
        #pragma unroll
        for (int rb = 0; rb < 4; rb++)
            #pragma unroll
            for (int v = 0; v < 4; v++) {
                const int r = 16 * rb + 4 * grp + v;
                const float rm = row_m[r], rr = row_rs[r];
                float a_ = 0.f, q_ = 0.f;
                #pragma unroll
                for (int cb = 0; cb < 2; cb++) {
                    float y = rr * (acc1[rb][cb][v] - rm * sv[cb]) + cv[cb];
                    y = y > 0.f ? y : (__expf(y) - 1.f);
                    acc1[rb][cb][v] = y;
                    a_ += y; q_ += y * y;
                }
                a_ += __shfl_xor(a_, 1); a_ += __shfl_xor(a_, 2); a_ += __shfl_xor(a_, 4); a_ += __shfl_xor(a_, 8);
                q_ += __shfl_xor(q_, 1); q_ += __shfl_xor(q_, 2); q_ += __shfl_xor(q_, 4); q_ += __shfl_xor(q_, 8);
                if (cl == 0) { psum[wv][r] = a_; psq[wv][r] = q_; }
            }
    }
    __syncthreads();   // gemm1 readers done -> frag reusable; psum published
    // ---- x2 fragment writes + LN2 finalize ----
    #pragma unroll
    for (int cb = 0; cb < 2; cb++) {
        const int c = cl + 16 * (2 * wv + cb);
        const int t = c >> 5, j = c & 7, sc = 16 * ((c >> 3) & 3);
        #pragma unroll
        for (int rb = 0; rb < 4; rb++)
            #pragma unroll
            for (int v = 0; v < 4; v++)
                frag[((t * 4 + rb) * 64 + (4 * grp + v + sc)) * 8 + j] = (half_t)acc1[rb][cb][v];
    }
    if (tid < 64) {
        float a_ = 0.f, q_ = 0.f;
        #pragma unroll
        for (int w = 0; w < 8; w++) { a_ += psum[w][tid]; q_ += psq[w][tid]; }
        const float mm = a_ * (1.f / 256.f);
        row_m[tid]  = mm;
        row_rs[tid] = 1.f / sqrtf(q_ * (1.f / 256.f) - mm * mm + LN_EPS);
    }
    __syncthreads();

    // ---- GEMM2: K=256 (8 t-steps), wave owns 16 cols ----
    f32x4 acc2[4];
    #pragma unroll
    for (int rb = 0; rb < 4; rb++) acc2[rb] = 0.f;
    {
        const half_t* wp = W2p + (size_t)(wv * 8) * 512 + lane * 8;
        half8_t bA = *(const half8_t*)(wp);
        #pragma unroll
        for (int t = 0; t < 8; t++) {
            const half8_t cur = bA;
            if (t < 7) bA = *(const half8_t*)(wp + (t + 1) * 512);
            half8_t af[4];
            #pragma unroll
            for (int rb = 0; rb < 4; rb++)
                af[rb] = *(const half8_t*)(&frag[((t * 4 + rb) * 64 + lane) * 8]);
            #pragma unroll
            for (int rb = 0; rb < 4; rb++)
                acc2[rb] = __builtin_amdgcn_mfma_f32_16x16x32_f16(af[rb], cur, acc2[rb], 0, 0, 0);
        }
    }

    // ---- epilogue2: LN2 fold + ELU + LN3 partials + folded W3 dot ----
    {
        const int c2i = cl + 16 * wv;
        const float sv = s2f[c2i], cv = c2f[c2i], w3v = w3f[c2i];
        #pragma unroll
        for (int rb = 0; rb < 4; rb++)
            #pragma unroll
            for (int v = 0; v < 4; v++) {
                const int r = 16 * rb + 4 * grp + v;
                const float rm = row_m[r], rr = row_rs[r];
                float y = rr * (acc2[rb][v] - rm * sv) + cv;
                y = y > 0.f ? y : (__expf(y) - 1.f);
                float a_ = y, q_ = y * y, d_ = y * w3v;
                a_ += __shfl_xor(a_, 1); a_ += __shfl_xor(a_, 2); a_ += __shfl_xor(a_, 4); a_ += __shfl_xor(a_, 8);
                q_ += __shfl_xor(q_, 1); q_ += __shfl_xor(q_, 2); q_ += __shfl_xor(q_, 4); q_ += __shfl_xor(q_, 8);
                d_ += __shfl_xor(d_, 1); d_ += __shfl_xor(d_, 2); d_ += __shfl_xor(d_, 4); d_ += __shfl_xor(d_, 8);
                if (cl == 0) { psum[wv][r] = a_; psq[wv][r] = q_; pdot[wv][r] = d_; }
            }
    }
    __syncthreads();
    if (tid < 64) {
        float a_ = 0.f, q_ = 0.f, d_ = 0.f;
        #pragma unroll
        for (int w = 0; w < 8; w++) { a_ += psum[w][tid]; q_ += psq[w][tid]; d_ += pdot[w][tid]; }
        const float mm = a_ * (1.f / 128.f);
        const float rs = 1.f / sqrtf(q_ * (1.f / 128.f) - mm * mm + LN_EPS);
        out[r0 + tid] = rs * (d_ - mm * f[1920]) + f[1921];
    }
}

extern "C" void kernel_launch(void* const* d_in, const int* in_sizes, int n_in,
                              void* d_out, int out_size, void* d_ws, size_t ws_size,
                              hipStream_t stream) {
    const float* x  = (const float*)d_in[0];
    const float* g0 = (const float*)d_in[1];
    const float* b0 = (const float*)d_in[2];
    const float* W0 = (const float*)d_in[3];
    const float* c0 = (const float*)d_in[4];
    const float* g1 = (const float*)d_in[5];
    const float* b1 = (const float*)d_in[6];
    const float* W1 = (const float*)d_in[7];
    const float* c1 = (const float*)d_in[8];
    const float* g2 = (const float*)d_in[9];
    const float* b2 = (const float*)d_in[10];
    const float* W2 = (const float*)d_in[11];
    const float* c2 = (const float*)d_in[12];
    const float* g3 = (const float*)d_in[13];
    const float* b3 = (const float*)d_in[14];
    const float* W3 = (const float*)d_in[15];
    const float* c3 = (const float*)d_in[16];

    half_t* ws = (half_t*)d_ws;            // packed weights: 557056 halves
    float*  f  = (float*)(ws + 557056);    // folded scalars: 1922 floats

    pack_weights<<<272, 256, 0, stream>>>(W0, g0, W1, g1, W2, g2, ws);
    fold_bias<<<225, 256, 0, stream>>>(W0, g0, b0, c0, W1, g1, b1, c1,
                                       W2, g2, b2, c2, W3, g3, b3, c3, f);

    const int nrows = in_sizes[0] / 768;   // 262144
    fused_mlp<<<nrows / 64, 512, 0, stream>>>(
        x, ws, ws + 393216, ws + 524288, f, (float*)d_out);
}